// Round 10
// baseline (197.573 us; speedup 1.0000x reference)
//
#include <hip/hip_runtime.h>
#include <hip/hip_bf16.h>
#include <math.h>

#define S_LEN 2048
#define HID 2048
#define NH 32
#define NKV 8
#define HD 64
#define WINDOW 1024
#define QBLK 128
#define QKVN 3072   // fused Q(2048) | K(512) | V(512) columns

typedef __attribute__((ext_vector_type(8))) short bx8;          // 8 bf16 (4 VGPRs) — MFMA A/B frag
typedef __attribute__((ext_vector_type(4))) float fx4;          // MFMA C/D frag
typedef __attribute__((ext_vector_type(8))) unsigned short us8; // 8 bf16 raw

// ---------------- RoPE tables (f64 on device, tiny) ----------------
__global__ void rope_table_kernel(float* __restrict__ cosT, float* __restrict__ sinT) {
    int idx = blockIdx.x * blockDim.x + threadIdx.x;  // s*32 + f
    if (idx >= S_LEN * 32) return;
    int s = idx >> 5, f = idx & 31;
    double inv = exp(-2.0 * (double)f / 64.0 * log(500000.0));
    double ang = (double)s * inv;
    cosT[idx] = (float)cos(ang);
    sinT[idx] = (float)sin(ang);
}

// ---------------- bf16 transpose: Vt[d][s] = QKV[s][2560+d] ----------------
__global__ void vtrans_kernel(const __hip_bfloat16* __restrict__ QKV, __hip_bfloat16* __restrict__ Vt) {
    __shared__ __hip_bfloat16 tile[32][33];
    int s0 = blockIdx.x * 32, d0 = blockIdx.y * 32;
    int tx = threadIdx.x, ty = threadIdx.y;  // 32 x 8
#pragma unroll
    for (int i = 0; i < 4; i++)
        tile[ty + 8 * i][tx] = QKV[(size_t)(s0 + ty + 8 * i) * QKVN + 2560 + d0 + tx];
    __syncthreads();
#pragma unroll
    for (int i = 0; i < 4; i++)
        Vt[(size_t)(d0 + ty + 8 * i) * S_LEN + s0 + tx] = tile[tx][ty + 8 * i];
}

// ---------------- bf16 transpose: Ab[s][hid] = Ot[hid][s] ----------------
__global__ void otrans_kernel(const __hip_bfloat16* __restrict__ Ot, __hip_bfloat16* __restrict__ Ab) {
    __shared__ __hip_bfloat16 tile[32][33];
    int h0 = blockIdx.x * 32, s0 = blockIdx.y * 32;
    int tx = threadIdx.x, ty = threadIdx.y;  // 32 x 8
#pragma unroll
    for (int i = 0; i < 4; i++)
        tile[ty + 8 * i][tx] = Ot[(size_t)(h0 + ty + 8 * i) * S_LEN + s0 + tx];
    __syncthreads();
#pragma unroll
    for (int i = 0; i < 4; i++)
        Ab[(size_t)(s0 + ty + 8 * i) * HID + h0 + tx] = tile[tx][ty + 8 * i];
}

// ---------------- fused-staging bf16 MFMA GEMM ----------------
// R10: reg-staged double-buffer. A read straight from f32 (QKV: hs) or bf16
// (Wo: Ab) row-major [M][K]; B read straight from f32 weights [K][N] with
// in-register transpose+convert. LDS layout identical to R9 (row*64B, slot
// XOR (row>>1)&3) so the MFMA read path is byte-for-byte unchanged.
template <int IS_QKV, int OUTBF16>
__global__ __launch_bounds__(256) void gemm_fused_kernel(const void* __restrict__ Ap,
                                                         const float* __restrict__ Bq,
                                                         const float* __restrict__ Bk,
                                                         const float* __restrict__ Bv,
                                                         void* __restrict__ Cp,
                                                         int nbx) {
    const int K = 2048;
    const int NOUT = IS_QKV ? QKVN : 2048;
    __shared__ __hip_bfloat16 As[2][4096];
    __shared__ __hip_bfloat16 Bs[2][4096];

    const int nwg = gridDim.x, cpx = nwg >> 3, bid = blockIdx.x;
    const int swz = (bid & 7) * cpx + (bid >> 3);
    const int bm = (swz / nbx) * 128, bn = (swz % nbx) * 128;

    // B source select (block-uniform)
    const float* Bsrc;
    int BN, bcol;
    if (IS_QKV) {
        if (bn < 2048)      { Bsrc = Bq; BN = 2048; bcol = bn; }
        else if (bn < 2560) { Bsrc = Bk; BN = 512;  bcol = bn - 2048; }
        else                { Bsrc = Bv; BN = 512;  bcol = bn - 2560; }
    } else { Bsrc = Bq; BN = 2048; bcol = bn; }

    const int t = threadIdx.x, w = t >> 6, l = t & 63;
    const int wr = (w >> 1) * 64, wc = (w & 1) * 64;
    const int lr = l & 15;
    const int rdslot = ((l >> 4) ^ ((lr >> 1) & 3)) * 8;   // element offset (8 bf16/slot)

    // A staging: thread owns row t>>1, k-half (t&1)*16 (16 elems = 2 slots)
    const int arow = t >> 1, ahk = t & 1;
    const int abyte0 = arow * 64 + ((((ahk * 2 + 0) ^ ((arow >> 1) & 3))) * 16);
    const int abyte1 = arow * 64 + ((((ahk * 2 + 1) ^ ((arow >> 1) & 3))) * 16);
    // B staging: thread owns 4k x 4n micro-tile: k = 4*(t&7)+i, n = 4*(t>>3)+jj
    const int bka = t & 7, bnb = (t >> 3) * 4;

    const float* Af = (const float*)Ap;
    const __hip_bfloat16* Abf = (const __hip_bfloat16*)Ap;

    float aregf[16];
    us8 aregb[2];
    float breg[4][4];

#define LOADA(kt)                                                                         \
    do {                                                                                  \
        const int kk = (kt) * 32 + ahk * 16;                                              \
        if (IS_QKV) {                                                                     \
            *(float4*)&aregf[0]  = *(const float4*)&Af[(size_t)(bm + arow) * K + kk];     \
            *(float4*)&aregf[4]  = *(const float4*)&Af[(size_t)(bm + arow) * K + kk + 4]; \
            *(float4*)&aregf[8]  = *(const float4*)&Af[(size_t)(bm + arow) * K + kk + 8]; \
            *(float4*)&aregf[12] = *(const float4*)&Af[(size_t)(bm + arow) * K + kk + 12];\
        } else {                                                                          \
            aregb[0] = *(const us8*)&Abf[(size_t)(bm + arow) * K + kk];                   \
            aregb[1] = *(const us8*)&Abf[(size_t)(bm + arow) * K + kk + 8];               \
        }                                                                                 \
    } while (0)

#define LOADB(kt)                                                                         \
    do {                                                                                  \
        const int kk = (kt) * 32 + bka * 4;                                               \
        _Pragma("unroll")                                                                 \
        for (int i = 0; i < 4; i++)                                                       \
            *(float4*)&breg[i][0] = *(const float4*)&Bsrc[(size_t)(kk + i) * BN + bcol + bnb]; \
    } while (0)

#define WRITEA(b)                                                                         \
    do {                                                                                  \
        char* base = (char*)As[(b)];                                                      \
        if (IS_QKV) {                                                                     \
            __hip_bfloat16 pk[16] __attribute__((aligned(16)));                           \
            _Pragma("unroll")                                                             \
            for (int m2 = 0; m2 < 16; m2++) pk[m2] = __float2bfloat16(aregf[m2]);         \
            *(bx8*)(base + abyte0) = *(bx8*)&pk[0];                                       \
            *(bx8*)(base + abyte1) = *(bx8*)&pk[8];                                       \
        } else {                                                                          \
            *(us8*)(base + abyte0) = aregb[0];                                            \
            *(us8*)(base + abyte1) = aregb[1];                                            \
        }                                                                                 \
    } while (0)

#define WRITEB(b)                                                                         \
    do {                                                                                  \
        char* base = (char*)Bs[(b)];                                                      \
        _Pragma("unroll")                                                                 \
        for (int jj = 0; jj < 4; jj++) {                                                  \
            const int n = bnb + jj;                                                       \
            __hip_bfloat16 pk[4] __attribute__((aligned(8)));                             \
            _Pragma("unroll")                                                             \
            for (int i2 = 0; i2 < 4; i2++) pk[i2] = __float2bfloat16(breg[i2][jj]);       \
            *(unsigned long long*)(base + n * 64 +                                        \
                (((bka >> 1) ^ ((n >> 1) & 3)) * 16) + (bka & 1) * 8) =                   \
                *(unsigned long long*)pk;                                                 \
        }                                                                                 \
    } while (0)

    fx4 acc[4][4];
#pragma unroll
    for (int m = 0; m < 4; m++)
#pragma unroll
        for (int n = 0; n < 4; n++) acc[m][n] = (fx4){0.f, 0.f, 0.f, 0.f};

    const int T = K / 32;   // 64

    LOADA(0); LOADB(0);
    WRITEA(0); WRITEB(0);
    LOADA(1); LOADB(1);
    __syncthreads();

    for (int i = 0; i < T; i++) {
        const int cur = i & 1;
        if (i + 1 < T) { WRITEA(cur ^ 1); WRITEB(cur ^ 1); }   // tile i+1 regs -> other buf
        if (i + 2 < T) { LOADA(i + 2); LOADB(i + 2); }         // issue tile i+2 loads

        bx8 af[4], bf[4];
#pragma unroll
        for (int m = 0; m < 4; m++)
            af[m] = *reinterpret_cast<const bx8*>(&As[cur][(wr + m * 16 + lr) * 32 + rdslot]);
#pragma unroll
        for (int n = 0; n < 4; n++)
            bf[n] = *reinterpret_cast<const bx8*>(&Bs[cur][(wc + n * 16 + lr) * 32 + rdslot]);
#pragma unroll
        for (int m = 0; m < 4; m++)
#pragma unroll
            for (int n = 0; n < 4; n++)
                acc[m][n] = __builtin_amdgcn_mfma_f32_16x16x32_bf16(af[m], bf[n], acc[m][n], 0, 0, 0);
        __syncthreads();
    }
#undef LOADA
#undef LOADB
#undef WRITEA
#undef WRITEB

    const int lq = (l >> 4) * 4;
#pragma unroll
    for (int m = 0; m < 4; m++)
#pragma unroll
        for (int n = 0; n < 4; n++)
#pragma unroll
            for (int r2 = 0; r2 < 4; r2++) {
                int row = bm + wr + m * 16 + lq + r2;
                int col = bn + wc + n * 16 + lr;
                float v = acc[m][n][r2];
                if (OUTBF16)
                    ((__hip_bfloat16*)Cp)[(size_t)row * NOUT + col] = __float2bfloat16(v);
                else
                    ((float*)Cp)[(size_t)row * NOUT + col] = v;
            }
}

// ---------------- RoPE in-place on fused QKV [S][3072] (Q cols 0-2047, K cols 2048-2559) ----------------
__global__ void rope_kernel(__hip_bfloat16* __restrict__ QKV,
                            const float* __restrict__ cosT, const float* __restrict__ sinT) {
    int idx = blockIdx.x * blockDim.x + threadIdx.x;  // s*(40*32) + head*32 + f
    int f = idx & 31;
    int head = (idx >> 5) % (NH + NKV);
    int s = idx / ((NH + NKV) * 32);
    if (s >= S_LEN) return;
    float c  = cosT[(s << 5) + f];
    float sn = sinT[(s << 5) + f];
    __hip_bfloat16* p = (head < NH) ? (QKV + (size_t)s * QKVN + head * HD)
                                    : (QKV + (size_t)s * QKVN + 2048 + (head - NH) * HD);
    float x1 = __bfloat162float(p[f]), x2 = __bfloat162float(p[f + 32]);
    p[f]      = __float2bfloat16(x1 * c - x2 * sn);
    p[f + 32] = __float2bfloat16(x2 * c + x1 * sn);
}

// ---------------- MFMA sliding-window flash attention, swapped-operand softmax (frozen R8) ----------------
__global__ __launch_bounds__(512, 4) void attn_kernel(const __hip_bfloat16* __restrict__ Q,
                                                      const __hip_bfloat16* __restrict__ Kg,
                                                      const __hip_bfloat16* __restrict__ Vtg,
                                                      __hip_bfloat16* __restrict__ Ot) {
    __shared__ __hip_bfloat16 Ks[64 * 64];
    __shared__ __hip_bfloat16 Vs[64 * 64];
    __shared__ __hip_bfloat16 Ps[QBLK * 64];

    const int bid = blockIdx.x;
    const int swz = (bid & 7) * 64 + (bid >> 3);
    const int h = swz >> 4, qi = swz & 15;
    const int qb = qi * QBLK;
    const int kvh = h >> 2;

    const int t = threadIdx.x, w = t >> 6, l = t & 63;
    const int lr = l & 15, g = l >> 4, lk = g * 8;
    const int qbw = qb + 16 * w;      // this wave's 16 q-rows
    const int prow = 16 * w + lr;     // this lane's q-row in Ps
    const int psz = (prow & 7) << 4;

    char* KsB = (char*)Ks;
    char* VsB = (char*)Vs;
    char* PsB = (char*)Ps;

    // hoisted Q fragments (B-operand; lane holds q-row lr)
    bx8 qa[2];
#pragma unroll
    for (int ks = 0; ks < 2; ks++)
        qa[ks] = *reinterpret_cast<const bx8*>(
            &Q[(size_t)(qbw + lr) * QKVN + h * HD + ks * 32 + lk]);

    fx4 ot[4];
#pragma unroll
    for (int n = 0; n < 4; n++) ot[n] = (fx4){0.f, 0.f, 0.f, 0.f};
    float mrow = -1e30f, srow = 0.f;

    const int k0_first = (qb >= 1024) ? (qb - 1024) : 0;
    const int k0_last  = qb + 64;
    const int wmax = qbw + 15;
    const int rowq = qbw + lr;        // this lane's q-row (global)

    // staging: 512 threads cover 64 rows x 8 us8-cols, one K + one V load each
    const int sr = t >> 3, sc8 = (t & 7) * 8;
    const int dst = sr * 128 + ((sc8 * 2) ^ ((sr & 7) << 4));

    for (int k0 = k0_first; k0 <= k0_last; k0 += 64) {
        us8 kv = *reinterpret_cast<const us8*>(&Kg[(size_t)(k0 + sr) * QKVN + kvh * HD + sc8]);
        us8 vv = *reinterpret_cast<const us8*>(&Vtg[(size_t)(kvh * HD + sr) * S_LEN + k0 + sc8]);
        *reinterpret_cast<us8*>(KsB + dst) = kv;
        *reinterpret_cast<us8*>(VsB + dst) = vv;
        __syncthreads();

        if (k0 <= wmax) {
            // K fragments (A-operand: rows = keys)
            bx8 kb[4][2];
#pragma unroll
            for (int n = 0; n < 4; n++)
#pragma unroll
                for (int ks = 0; ks < 2; ks++) {
                    int row = 16 * n + lr;
                    kb[n][ks] = *reinterpret_cast<const bx8*>(
                        KsB + row * 128 + (((ks * 64) + 16 * g) ^ ((row & 7) << 4)));
                }
            // S^T = K · Q^T : rows=keys (16n+4g+r), cols=q (lr)
            fx4 sc[4];
#pragma unroll
            for (int n = 0; n < 4; n++) {
                sc[n] = __builtin_amdgcn_mfma_f32_16x16x32_bf16(kb[n][0], qa[0],
                                                                (fx4){0.f, 0.f, 0.f, 0.f}, 0, 0, 0);
                sc[n] = __builtin_amdgcn_mfma_f32_16x16x32_bf16(kb[n][1], qa[1], sc[n], 0, 0, 0);
            }
            // scale + sliding-window mask (interior tiles skip the mask)
            const bool interior = (k0 + 63 <= qbw) && (k0 >= qbw - 1008);
            if (interior) {
#pragma unroll
                for (int n = 0; n < 4; n++)
#pragma unroll
                    for (int r = 0; r < 4; r++) sc[n][r] *= 0.125f;
            } else {
#pragma unroll
                for (int n = 0; n < 4; n++)
#pragma unroll
                    for (int r = 0; r < 4; r++) {
                        int key = k0 + 16 * n + 4 * g + r;
                        bool valid = (key <= rowq) && (key >= rowq - (WINDOW - 1));
                        sc[n][r] = valid ? sc[n][r] * 0.125f : -1e30f;
                    }
            }
            // in-register row max
            float tmax = fmaxf(fmaxf(sc[0][0], sc[0][1]), fmaxf(sc[0][2], sc[0][3]));
#pragma unroll
            for (int n = 1; n < 4; n++)
                tmax = fmaxf(tmax, fmaxf(fmaxf(sc[n][0], sc[n][1]), fmaxf(sc[n][2], sc[n][3])));
            tmax = fmaxf(tmax, __shfl_xor(tmax, 16));
            tmax = fmaxf(tmax, __shfl_xor(tmax, 32));
            float mn = fmaxf(mrow, tmax);
            float fs = __expf(mrow - mn);
            mrow = mn;
            // exp + P^T write (packed b64, lane's own row) + sum
            float ps = 0.f;
#pragma unroll
            for (int n = 0; n < 4; n++) {
#pragma unroll
                for (int r = 0; r < 4; r++) {
                    float p = __expf(sc[n][r] - mn);
                    sc[n][r] = p;
                    ps += p;
                }
                __hip_bfloat16 pk[4] __attribute__((aligned(8)));
                pk[0] = __float2bfloat16(sc[n][0]); pk[1] = __float2bfloat16(sc[n][1]);
                pk[2] = __float2bfloat16(sc[n][2]); pk[3] = __float2bfloat16(sc[n][3]);
                *reinterpret_cast<unsigned long long*>(PsB + prow * 128 + ((32 * n + 8 * g) ^ psz)) =
                    *reinterpret_cast<unsigned long long*>(pk);
            }
            ps += __shfl_xor(ps, 16);
            ps += __shfl_xor(ps, 32);
            srow = srow * fs + ps;
#pragma unroll
            for (int n = 0; n < 4; n++)
#pragma unroll
                for (int r = 0; r < 4; r++) ot[n][r] *= fs;
            // V fragments (A-operand: rows = d) + P fragments (B-operand: rows = q)
            bx8 vb[4][2];
#pragma unroll
            for (int n = 0; n < 4; n++)
#pragma unroll
                for (int ks = 0; ks < 2; ks++) {
                    int row = 16 * n + lr;
                    vb[n][ks] = *reinterpret_cast<const bx8*>(
                        VsB + row * 128 + (((ks * 64) + 16 * g) ^ ((row & 7) << 4)));
                }
            bx8 pb[2];
#pragma unroll
            for (int ks = 0; ks < 2; ks++)
                pb[ks] = *reinterpret_cast<const bx8*>(
                    PsB + prow * 128 + (((ks * 64) + 16 * g) ^ psz));
            // O^T += V^T · P : rows=d (16n+4g+r), cols=q (lr)
#pragma unroll
            for (int n = 0; n < 4; n++) {
                ot[n] = __builtin_amdgcn_mfma_f32_16x16x32_bf16(vb[n][0], pb[0], ot[n], 0, 0, 0);
                ot[n] = __builtin_amdgcn_mfma_f32_16x16x32_bf16(vb[n][1], pb[1], ot[n], 0, 0, 0);
            }
        }
        __syncthreads();
    }

    // ---- epilogue: normalize (one inv per lane) + store O^T ----
    const float inv = 1.f / srow;
#pragma unroll
    for (int n = 0; n < 4; n++)
#pragma unroll
        for (int r = 0; r < 4; r++) {
            int d = h * HD + 16 * n + 4 * g + r;
            Ot[(size_t)d * S_LEN + qbw + lr] = __float2bfloat16(ot[n][r] * inv);
        }
}

extern "C" void kernel_launch(void* const* d_in, const int* in_sizes, int n_in,
                              void* d_out, int out_size, void* d_ws, size_t ws_size,
                              hipStream_t stream) {
    const float* hs = (const float*)d_in[0];
    const float* Wq = (const float*)d_in[1];
    const float* Wk = (const float*)d_in[2];
    const float* Wv = (const float*)d_in[3];
    const float* Wo = (const float*)d_in[4];

    float* ws   = (float*)d_ws;
    float* cosT = ws;                  // 65536 f32
    float* sinT = cosT + 65536;        // 65536 f32
    __hip_bfloat16* QKVb = (__hip_bfloat16*)(sinT + 65536);   // [2048][3072]
    __hip_bfloat16* Vt   = QKVb + 6291456;                    // [512][2048]
    __hip_bfloat16* Ot   = Vt + 1048576;                      // [2048][2048] O^T
    __hip_bfloat16* Ab   = Ot + 4194304;                      // [2048][2048]

    rope_table_kernel<<<(S_LEN * 32) / 256, 256, 0, stream>>>(cosT, sinT);

    // fused QKV projection straight from f32 inputs (conv/convT eliminated)
    gemm_fused_kernel<1, 1><<<384, 256, 0, stream>>>(hs, Wq, Wk, Wv, QKVb, 24);

    // RoPE on Q and K (fused QKV layout)
    rope_kernel<<<(S_LEN * (NH + NKV) * 32) / 256, 256, 0, stream>>>(QKVb, cosT, sinT);

    vtrans_kernel<<<dim3(64, 16), dim3(32, 8), 0, stream>>>(QKVb, Vt);

    attn_kernel<<<512, 512, 0, stream>>>(QKVb, QKVb + 2048, Vt, Ot);

    // restore row-major O for the Wo gemm
    otrans_kernel<<<dim3(64, 64), dim3(32, 8), 0, stream>>>(Ot, Ab);

    // output projection straight from f32 Wo
    gemm_fused_kernel<0, 0><<<256, 256, 0, stream>>>(Ab, Wo, nullptr, nullptr, d_out, 16);
}

// Round 12
// 155.305 us; speedup vs baseline: 1.2722x; 1.2722x over previous
//
#include <hip/hip_runtime.h>
#include <hip/hip_bf16.h>
#include <math.h>

#define S_LEN 2048
#define HID 2048
#define NH 32
#define NKV 8
#define HD 64
#define WINDOW 1024
#define QBLK 128
#define QKVN 3072   // fused Q(2048) | K(512) | V(512) columns

typedef __attribute__((ext_vector_type(8))) short bx8;          // 8 bf16 (4 VGPRs) — MFMA A/B frag
typedef __attribute__((ext_vector_type(4))) float fx4;          // MFMA C/D frag
typedef __attribute__((ext_vector_type(8))) unsigned short us8; // 8 bf16 raw

#define GL_LDS16(gp, lp) \
    __builtin_amdgcn_global_load_lds((__attribute__((address_space(1))) const void*)(gp), \
                                     (__attribute__((address_space(3))) void*)(lp), 16, 0, 0)

// ---------------- prep: rope tables + hs conv + 4 weight transposes, ONE dispatch ----------------
// blocks: [0,256) rope_table | [256,2304) conv hs | then convT: Wq 4096, Wk 1024, Wv 1024, Wo 4096
__global__ __launch_bounds__(256) void prep_kernel(const float* __restrict__ hs,
                                                   const float* __restrict__ Wq,
                                                   const float* __restrict__ Wk,
                                                   const float* __restrict__ Wv,
                                                   const float* __restrict__ Wo,
                                                   float* __restrict__ cosT, float* __restrict__ sinT,
                                                   __hip_bfloat16* __restrict__ hsb,
                                                   __hip_bfloat16* __restrict__ WqkvT,
                                                   __hip_bfloat16* __restrict__ WoT) {
    __shared__ float tile[32][33];
    int b = blockIdx.x, t = threadIdx.x;
    if (b < 256) {
        int idx = b * 256 + t;           // s*32 + f
        int s = idx >> 5, f = idx & 31;
        double inv = exp(-2.0 * (double)f / 64.0 * log(500000.0));
        double ang = (double)s * inv;
        cosT[idx] = (float)cos(ang);
        sinT[idx] = (float)sin(ang);
        return;
    }
    b -= 256;
    if (b < 2048) {
        int i = (b * 256 + t) * 8;
        float4 a = *reinterpret_cast<const float4*>(&hs[i]);
        float4 c = *reinterpret_cast<const float4*>(&hs[i + 4]);
        __hip_bfloat16 o[8] __attribute__((aligned(16)));
        o[0] = __float2bfloat16(a.x); o[1] = __float2bfloat16(a.y);
        o[2] = __float2bfloat16(a.z); o[3] = __float2bfloat16(a.w);
        o[4] = __float2bfloat16(c.x); o[5] = __float2bfloat16(c.y);
        o[6] = __float2bfloat16(c.z); o[7] = __float2bfloat16(c.w);
        *reinterpret_cast<bx8*>(&hsb[i]) = *reinterpret_cast<bx8*>(o);
        return;
    }
    b -= 2048;
    const float* src; __hip_bfloat16* dst; int Nd, bx, by;
    if (b < 4096)      { src = Wq; dst = WqkvT;                        Nd = 2048; bx = b & 63; by = b >> 6; }
    else if (b < 5120) { b -= 4096; src = Wk; dst = WqkvT + (size_t)2048 * 2048; Nd = 512; bx = b & 15; by = b >> 4; }
    else if (b < 6144) { b -= 5120; src = Wv; dst = WqkvT + (size_t)2560 * 2048; Nd = 512; bx = b & 15; by = b >> 4; }
    else               { b -= 6144; src = Wo; dst = WoT;               Nd = 2048; bx = b & 63; by = b >> 6; }
    int n0 = bx * 32, k0 = by * 32, tx = t & 31, ty = t >> 5;  // 32 x 8
#pragma unroll
    for (int i = 0; i < 4; i++)
        tile[ty + 8 * i][tx] = src[(size_t)(k0 + ty + 8 * i) * Nd + n0 + tx];
    __syncthreads();
#pragma unroll
    for (int i = 0; i < 4; i++)
        dst[(size_t)(n0 + ty + 8 * i) * 2048 + k0 + tx] = __float2bfloat16(tile[tx][ty + 8 * i]);
}

// ---------------- rope (Q+K) + vtrans, ONE dispatch ----------------
// blocks: [0,10240) rope | [10240,11264) vtrans
__global__ __launch_bounds__(256) void ropev_kernel(__hip_bfloat16* __restrict__ QKV,
                                                    __hip_bfloat16* __restrict__ Vt,
                                                    const float* __restrict__ cosT,
                                                    const float* __restrict__ sinT) {
    __shared__ __hip_bfloat16 tile[32][33];
    int b = blockIdx.x, t = threadIdx.x;
    if (b < 10240) {
        int idx = b * 256 + t;           // s*(40*32) + head*32 + f
        int f = idx & 31;
        int head = (idx >> 5) % (NH + NKV);
        int s = idx / ((NH + NKV) * 32);
        float c  = cosT[(s << 5) + f];
        float sn = sinT[(s << 5) + f];
        __hip_bfloat16* p = (head < NH) ? (QKV + (size_t)s * QKVN + head * HD)
                                        : (QKV + (size_t)s * QKVN + 2048 + (head - NH) * HD);
        float x1 = __bfloat162float(p[f]), x2 = __bfloat162float(p[f + 32]);
        p[f]      = __float2bfloat16(x1 * c - x2 * sn);
        p[f + 32] = __float2bfloat16(x2 * c + x1 * sn);
        return;
    }
    b -= 10240;
    int s0 = (b & 63) * 32, d0 = (b >> 6) * 32;
    int tx = t & 31, ty = t >> 5;  // 32 x 8
#pragma unroll
    for (int i = 0; i < 4; i++)
        tile[ty + 8 * i][tx] = QKV[(size_t)(s0 + ty + 8 * i) * QKVN + 2560 + d0 + tx];
    __syncthreads();
#pragma unroll
    for (int i = 0; i < 4; i++)
        Vt[(size_t)(d0 + ty + 8 * i) * S_LEN + s0 + tx] = tile[tx][ty + 8 * i];
}

// ---------------- pipelined bf16 MFMA GEMM with LDS bank swizzle (frozen R9) ----------------
template <int OUTBF16>
__global__ __launch_bounds__(256) void gemm_pipe_kernel(const __hip_bfloat16* __restrict__ A,
                                                        const __hip_bfloat16* __restrict__ Bt,
                                                        void* __restrict__ Cp,
                                                        int M, int N, int K, int nbx) {
    __shared__ __hip_bfloat16 As[3][4096];
    __shared__ __hip_bfloat16 Bs[3][4096];

    const int nwg = gridDim.x, cpx = nwg >> 3, bid = blockIdx.x;
    const int swz = (bid & 7) * cpx + (bid >> 3);
    const int bm = (swz / nbx) * 128, bn = (swz % nbx) * 128;

    const int t = threadIdx.x, w = t >> 6, l = t & 63;
    const int wr = (w >> 1) * 64, wc = (w & 1) * 64;
    const int lr = l & 15;
    const int rdslot = (((l >> 4) ^ ((lr >> 1) & 3))) * 8;
    const int srow = w * 16 + (l >> 2);
    const int scol = (((l & 3) ^ ((l >> 3) & 3))) * 8;
    const int ldsoff = w * 512;

    const __hip_bfloat16* ga0 = A + (size_t)(bm + srow) * K + scol;
    const __hip_bfloat16* gb0 = Bt + (size_t)(bn + srow) * K + scol;
    const size_t half = (size_t)64 * K;

    fx4 acc[4][4];
#pragma unroll
    for (int m = 0; m < 4; m++)
#pragma unroll
        for (int n = 0; n < 4; n++) acc[m][n] = (fx4){0.f, 0.f, 0.f, 0.f};

    const int T = K >> 5;

#define STAGE(kt, b)                                              \
    do {                                                          \
        const __hip_bfloat16* ga = ga0 + (kt) * 32;               \
        const __hip_bfloat16* gb = gb0 + (kt) * 32;               \
        GL_LDS16(ga,        &As[(b)][ldsoff]);                    \
        GL_LDS16(ga + half, &As[(b)][2048 + ldsoff]);             \
        GL_LDS16(gb,        &Bs[(b)][ldsoff]);                    \
        GL_LDS16(gb + half, &Bs[(b)][2048 + ldsoff]);             \
    } while (0)

    STAGE(0, 0);
    STAGE(1, 1);

    for (int i = 0; i < T; i++) {
        const int r = i % 3;
        if (i + 1 < T) asm volatile("s_waitcnt vmcnt(4)" ::: "memory");
        else           asm volatile("s_waitcnt vmcnt(0)" ::: "memory");
        __builtin_amdgcn_s_barrier();
        asm volatile("" ::: "memory");
        if (i + 2 < T) STAGE(i + 2, (i + 2) % 3);

        bx8 af[4], bf[4];
#pragma unroll
        for (int m = 0; m < 4; m++)
            af[m] = *reinterpret_cast<const bx8*>(&As[r][(wr + m * 16 + lr) * 32 + rdslot]);
#pragma unroll
        for (int n = 0; n < 4; n++)
            bf[n] = *reinterpret_cast<const bx8*>(&Bs[r][(wc + n * 16 + lr) * 32 + rdslot]);
#pragma unroll
        for (int m = 0; m < 4; m++)
#pragma unroll
            for (int n = 0; n < 4; n++)
                acc[m][n] = __builtin_amdgcn_mfma_f32_16x16x32_bf16(af[m], bf[n], acc[m][n], 0, 0, 0);
    }
#undef STAGE

    const int lq = (l >> 4) * 4;
#pragma unroll
    for (int m = 0; m < 4; m++)
#pragma unroll
        for (int n = 0; n < 4; n++)
#pragma unroll
            for (int r2 = 0; r2 < 4; r2++) {
                int row = bm + wr + m * 16 + lq + r2;
                int col = bn + wc + n * 16 + lr;
                float v = acc[m][n][r2];
                if (OUTBF16)
                    ((__hip_bfloat16*)Cp)[(size_t)row * N + col] = __float2bfloat16(v);
                else
                    ((float*)Cp)[(size_t)row * N + col] = v;
            }
}

// ---------------- MFMA sliding-window flash attention, swapped-operand softmax ----------------
// R12: R11 with the epilogue drain fixed — 128 rows x 8 us8-chunks (two passes
// of 512 threads), was 4 chunks (half the row, d=32..63 left unwritten).
__global__ __launch_bounds__(512, 4) void attn_kernel(const __hip_bfloat16* __restrict__ Q,
                                                      const __hip_bfloat16* __restrict__ Kg,
                                                      const __hip_bfloat16* __restrict__ Vtg,
                                                      __hip_bfloat16* __restrict__ Ab) {
    __shared__ __hip_bfloat16 Ks[64 * 64];
    __shared__ __hip_bfloat16 Vs[64 * 64];
    __shared__ __hip_bfloat16 Ps[QBLK * 64];

    const int bid = blockIdx.x;
    const int swz = (bid & 7) * 64 + (bid >> 3);
    const int h = swz >> 4, qi = swz & 15;
    const int qb = qi * QBLK;
    const int kvh = h >> 2;

    const int t = threadIdx.x, w = t >> 6, l = t & 63;
    const int lr = l & 15, g = l >> 4, lk = g * 8;
    const int qbw = qb + 16 * w;      // this wave's 16 q-rows
    const int prow = 16 * w + lr;     // this lane's q-row in Ps
    const int psz = (prow & 7) << 4;

    char* KsB = (char*)Ks;
    char* VsB = (char*)Vs;
    char* PsB = (char*)Ps;

    // hoisted Q fragments (B-operand; lane holds q-row lr)
    bx8 qa[2];
#pragma unroll
    for (int ks = 0; ks < 2; ks++)
        qa[ks] = *reinterpret_cast<const bx8*>(
            &Q[(size_t)(qbw + lr) * QKVN + h * HD + ks * 32 + lk]);

    fx4 ot[4];
#pragma unroll
    for (int n = 0; n < 4; n++) ot[n] = (fx4){0.f, 0.f, 0.f, 0.f};
    float mrow = -1e30f, srow = 0.f;

    const int k0_first = (qb >= 1024) ? (qb - 1024) : 0;
    const int k0_last  = qb + 64;
    const int wmax = qbw + 15;
    const int rowq = qbw + lr;        // this lane's q-row (global)

    // staging: 512 threads cover 64 rows x 8 us8-cols, one K + one V load each
    const int sr = t >> 3, sc8 = (t & 7) * 8;
    const int dst = sr * 128 + ((sc8 * 2) ^ ((sr & 7) << 4));

    for (int k0 = k0_first; k0 <= k0_last; k0 += 64) {
        us8 kv = *reinterpret_cast<const us8*>(&Kg[(size_t)(k0 + sr) * QKVN + kvh * HD + sc8]);
        us8 vv = *reinterpret_cast<const us8*>(&Vtg[(size_t)(kvh * HD + sr) * S_LEN + k0 + sc8]);
        *reinterpret_cast<us8*>(KsB + dst) = kv;
        *reinterpret_cast<us8*>(VsB + dst) = vv;
        __syncthreads();

        if (k0 <= wmax) {
            // K fragments (A-operand: rows = keys)
            bx8 kb[4][2];
#pragma unroll
            for (int n = 0; n < 4; n++)
#pragma unroll
                for (int ks = 0; ks < 2; ks++) {
                    int row = 16 * n + lr;
                    kb[n][ks] = *reinterpret_cast<const bx8*>(
                        KsB + row * 128 + (((ks * 64) + 16 * g) ^ ((row & 7) << 4)));
                }
            // S^T = K · Q^T : rows=keys (16n+4g+r), cols=q (lr)
            fx4 sc[4];
#pragma unroll
            for (int n = 0; n < 4; n++) {
                sc[n] = __builtin_amdgcn_mfma_f32_16x16x32_bf16(kb[n][0], qa[0],
                                                                (fx4){0.f, 0.f, 0.f, 0.f}, 0, 0, 0);
                sc[n] = __builtin_amdgcn_mfma_f32_16x16x32_bf16(kb[n][1], qa[1], sc[n], 0, 0, 0);
            }
            // scale + sliding-window mask (interior tiles skip the mask)
            const bool interior = (k0 + 63 <= qbw) && (k0 >= qbw - 1008);
            if (interior) {
#pragma unroll
                for (int n = 0; n < 4; n++)
#pragma unroll
                    for (int r = 0; r < 4; r++) sc[n][r] *= 0.125f;
            } else {
#pragma unroll
                for (int n = 0; n < 4; n++)
#pragma unroll
                    for (int r = 0; r < 4; r++) {
                        int key = k0 + 16 * n + 4 * g + r;
                        bool valid = (key <= rowq) && (key >= rowq - (WINDOW - 1));
                        sc[n][r] = valid ? sc[n][r] * 0.125f : -1e30f;
                    }
            }
            // in-register row max
            float tmax = fmaxf(fmaxf(sc[0][0], sc[0][1]), fmaxf(sc[0][2], sc[0][3]));
#pragma unroll
            for (int n = 1; n < 4; n++)
                tmax = fmaxf(tmax, fmaxf(fmaxf(sc[n][0], sc[n][1]), fmaxf(sc[n][2], sc[n][3])));
            tmax = fmaxf(tmax, __shfl_xor(tmax, 16));
            tmax = fmaxf(tmax, __shfl_xor(tmax, 32));
            float mn = fmaxf(mrow, tmax);
            float fs = __expf(mrow - mn);
            mrow = mn;
            // exp + P^T write (packed b64, lane's own row) + sum
            float ps = 0.f;
#pragma unroll
            for (int n = 0; n < 4; n++) {
#pragma unroll
                for (int r = 0; r < 4; r++) {
                    float p = __expf(sc[n][r] - mn);
                    sc[n][r] = p;
                    ps += p;
                }
                __hip_bfloat16 pk[4] __attribute__((aligned(8)));
                pk[0] = __float2bfloat16(sc[n][0]); pk[1] = __float2bfloat16(sc[n][1]);
                pk[2] = __float2bfloat16(sc[n][2]); pk[3] = __float2bfloat16(sc[n][3]);
                *reinterpret_cast<unsigned long long*>(PsB + prow * 128 + ((32 * n + 8 * g) ^ psz)) =
                    *reinterpret_cast<unsigned long long*>(pk);
            }
            ps += __shfl_xor(ps, 16);
            ps += __shfl_xor(ps, 32);
            srow = srow * fs + ps;
#pragma unroll
            for (int n = 0; n < 4; n++)
#pragma unroll
                for (int r = 0; r < 4; r++) ot[n][r] *= fs;
            // V fragments (A-operand: rows = d) + P fragments (B-operand: rows = q)
            bx8 vb[4][2];
#pragma unroll
            for (int n = 0; n < 4; n++)
#pragma unroll
                for (int ks = 0; ks < 2; ks++) {
                    int row = 16 * n + lr;
                    vb[n][ks] = *reinterpret_cast<const bx8*>(
                        VsB + row * 128 + (((ks * 64) + 16 * g) ^ ((row & 7) << 4)));
                }
            bx8 pb[2];
#pragma unroll
            for (int ks = 0; ks < 2; ks++)
                pb[ks] = *reinterpret_cast<const bx8*>(
                    PsB + prow * 128 + (((ks * 64) + 16 * g) ^ psz));
            // O^T += V^T · P : rows=d (16n+4g+r), cols=q (lr)
#pragma unroll
            for (int n = 0; n < 4; n++) {
                ot[n] = __builtin_amdgcn_mfma_f32_16x16x32_bf16(vb[n][0], pb[0], ot[n], 0, 0, 0);
                ot[n] = __builtin_amdgcn_mfma_f32_16x16x32_bf16(vb[n][1], pb[1], ot[n], 0, 0, 0);
            }
        }
        __syncthreads();
    }

    // ---- epilogue: normalize, O^T frags -> Ps as [q][d] (b64+XOR, same as P-write),
    // then cooperative coalesced row-major store to Ab (128 rows x 8 chunks) ----
    const float inv = 1.f / srow;
#pragma unroll
    for (int n = 0; n < 4; n++) {
        __hip_bfloat16 pk[4] __attribute__((aligned(8)));
#pragma unroll
        for (int r = 0; r < 4; r++) pk[r] = __float2bfloat16(ot[n][r] * inv);
        *reinterpret_cast<unsigned long long*>(PsB + prow * 128 + ((32 * n + 8 * g) ^ psz)) =
            *reinterpret_cast<unsigned long long*>(pk);
    }
    __syncthreads();
#pragma unroll
    for (int j = 0; j < 2; j++) {
        const int row = (t >> 3) + 64 * j, c = t & 7;   // 128 rows x 8 us8-chunks
        us8 v = *reinterpret_cast<const us8*>(PsB + row * 128 + ((c * 16) ^ ((row & 7) << 4)));
        *reinterpret_cast<us8*>(&Ab[(size_t)(qb + row) * HID + h * HD + c * 8]) = v;
    }
}

extern "C" void kernel_launch(void* const* d_in, const int* in_sizes, int n_in,
                              void* d_out, int out_size, void* d_ws, size_t ws_size,
                              hipStream_t stream) {
    const float* hs = (const float*)d_in[0];
    const float* Wq = (const float*)d_in[1];
    const float* Wk = (const float*)d_in[2];
    const float* Wv = (const float*)d_in[3];
    const float* Wo = (const float*)d_in[4];

    float* ws   = (float*)d_ws;
    float* cosT = ws;                  // 65536 f32
    float* sinT = cosT + 65536;        // 65536 f32
    __hip_bfloat16* hsb    = (__hip_bfloat16*)(sinT + 65536);   // [2048][2048]
    __hip_bfloat16* WqkvT  = hsb + 4194304;                     // [3072][2048]: Wq|Wk|Wv rows
    __hip_bfloat16* WoT    = WqkvT + 6291456;                   // [2048][2048]
    __hip_bfloat16* QKVb   = WoT + 4194304;                     // [2048][3072]
    __hip_bfloat16* Vt     = QKVb + 6291456;                    // [512][2048]
    __hip_bfloat16* Ab     = hsb;                               // alias: hsb dead after QKV gemm

    // prep: tables + hs->bf16 + weight transposes (one dispatch)
    prep_kernel<<<12544, 256, 0, stream>>>(hs, Wq, Wk, Wv, Wo, cosT, sinT, hsb, WqkvT, WoT);

    // fused QKV projection: [2048][3072] = hsb @ WqkvT^T
    gemm_pipe_kernel<1><<<384, 256, 0, stream>>>(hsb, WqkvT, QKVb, 2048, QKVN, 2048, 24);

    // RoPE (Q+K) + V transpose (one dispatch)
    ropev_kernel<<<11264, 256, 0, stream>>>(QKVb, Vt, cosT, sinT);

    // attention writes row-major Ab directly (otrans eliminated)
    attn_kernel<<<512, 512, 0, stream>>>(QKVb, QKVb + 2048, Vt, Ab);

    // output projection: d_out = Ab @ WoT^T
    gemm_pipe_kernel<0><<<256, 256, 0, stream>>>(Ab, WoT, d_out, 2048, 2048, 2048, 16);
}

// Round 13
// 145.345 us; speedup vs baseline: 1.3593x; 1.0685x over previous
//
#include <hip/hip_runtime.h>
#include <hip/hip_bf16.h>
#include <math.h>

#define S_LEN 2048
#define HID 2048
#define NH 32
#define NKV 8
#define HD 64
#define WINDOW 1024
#define QBLK 128
#define QKVN 3072   // fused Q(2048) | K(512) | V(512) columns

typedef __attribute__((ext_vector_type(8))) short bx8;          // 8 bf16 (4 VGPRs) — MFMA A/B frag
typedef __attribute__((ext_vector_type(4))) float fx4;          // MFMA C/D frag
typedef __attribute__((ext_vector_type(8))) unsigned short us8; // 8 bf16 raw

#define GL_LDS16(gp, lp) \
    __builtin_amdgcn_global_load_lds((__attribute__((address_space(1))) const void*)(gp), \
                                     (__attribute__((address_space(3))) void*)(lp), 16, 0, 0)

// ---------------- prep: rope tables + hs conv + 4 weight transposes, ONE dispatch ----------------
__global__ __launch_bounds__(256) void prep_kernel(const float* __restrict__ hs,
                                                   const float* __restrict__ Wq,
                                                   const float* __restrict__ Wk,
                                                   const float* __restrict__ Wv,
                                                   const float* __restrict__ Wo,
                                                   float* __restrict__ cosT, float* __restrict__ sinT,
                                                   __hip_bfloat16* __restrict__ hsb,
                                                   __hip_bfloat16* __restrict__ WqkvT,
                                                   __hip_bfloat16* __restrict__ WoT) {
    __shared__ float tile[32][33];
    int b = blockIdx.x, t = threadIdx.x;
    if (b < 256) {
        int idx = b * 256 + t;           // s*32 + f
        int s = idx >> 5, f = idx & 31;
        double inv = exp(-2.0 * (double)f / 64.0 * log(500000.0));
        double ang = (double)s * inv;
        cosT[idx] = (float)cos(ang);
        sinT[idx] = (float)sin(ang);
        return;
    }
    b -= 256;
    if (b < 2048) {
        int i = (b * 256 + t) * 8;
        float4 a = *reinterpret_cast<const float4*>(&hs[i]);
        float4 c = *reinterpret_cast<const float4*>(&hs[i + 4]);
        __hip_bfloat16 o[8] __attribute__((aligned(16)));
        o[0] = __float2bfloat16(a.x); o[1] = __float2bfloat16(a.y);
        o[2] = __float2bfloat16(a.z); o[3] = __float2bfloat16(a.w);
        o[4] = __float2bfloat16(c.x); o[5] = __float2bfloat16(c.y);
        o[6] = __float2bfloat16(c.z); o[7] = __float2bfloat16(c.w);
        *reinterpret_cast<bx8*>(&hsb[i]) = *reinterpret_cast<bx8*>(o);
        return;
    }
    b -= 2048;
    const float* src; __hip_bfloat16* dst; int Nd, bx, by;
    if (b < 4096)      { src = Wq; dst = WqkvT;                        Nd = 2048; bx = b & 63; by = b >> 6; }
    else if (b < 5120) { b -= 4096; src = Wk; dst = WqkvT + (size_t)2048 * 2048; Nd = 512; bx = b & 15; by = b >> 4; }
    else if (b < 6144) { b -= 5120; src = Wv; dst = WqkvT + (size_t)2560 * 2048; Nd = 512; bx = b & 15; by = b >> 4; }
    else               { b -= 6144; src = Wo; dst = WoT;               Nd = 2048; bx = b & 63; by = b >> 6; }
    int n0 = bx * 32, k0 = by * 32, tx = t & 31, ty = t >> 5;  // 32 x 8
#pragma unroll
    for (int i = 0; i < 4; i++)
        tile[ty + 8 * i][tx] = src[(size_t)(k0 + ty + 8 * i) * Nd + n0 + tx];
    __syncthreads();
#pragma unroll
    for (int i = 0; i < 4; i++)
        dst[(size_t)(n0 + ty + 8 * i) * 2048 + k0 + tx] = __float2bfloat16(tile[tx][ty + 8 * i]);
}

// ---------------- rope (Q+K) + vtrans, ONE dispatch ----------------
__global__ __launch_bounds__(256) void ropev_kernel(__hip_bfloat16* __restrict__ QKV,
                                                    __hip_bfloat16* __restrict__ Vt,
                                                    const float* __restrict__ cosT,
                                                    const float* __restrict__ sinT) {
    __shared__ __hip_bfloat16 tile[32][33];
    int b = blockIdx.x, t = threadIdx.x;
    if (b < 10240) {
        int idx = b * 256 + t;           // s*(40*32) + head*32 + f
        int f = idx & 31;
        int head = (idx >> 5) % (NH + NKV);
        int s = idx / ((NH + NKV) * 32);
        float c  = cosT[(s << 5) + f];
        float sn = sinT[(s << 5) + f];
        __hip_bfloat16* p = (head < NH) ? (QKV + (size_t)s * QKVN + head * HD)
                                        : (QKV + (size_t)s * QKVN + 2048 + (head - NH) * HD);
        float x1 = __bfloat162float(p[f]), x2 = __bfloat162float(p[f + 32]);
        p[f]      = __float2bfloat16(x1 * c - x2 * sn);
        p[f + 32] = __float2bfloat16(x2 * c + x1 * sn);
        return;
    }
    b -= 10240;
    int s0 = (b & 63) * 32, d0 = (b >> 6) * 32;
    int tx = t & 31, ty = t >> 5;  // 32 x 8
#pragma unroll
    for (int i = 0; i < 4; i++)
        tile[ty + 8 * i][tx] = QKV[(size_t)(s0 + ty + 8 * i) * QKVN + 2560 + d0 + tx];
    __syncthreads();
#pragma unroll
    for (int i = 0; i < 4; i++)
        Vt[(size_t)(d0 + ty + 8 * i) * S_LEN + s0 + tx] = tile[tx][ty + 8 * i];
}

// ---------------- pipelined bf16 MFMA GEMM, 64x128 tile (R13) ----------------
// 4 waves, each owns 32x64 (acc[2][4]). Same swizzle/staging algebra as R9;
// smaller tile -> 2x grid -> 3-4 blocks/CU for cross-block latency hiding.
template <int OUTBF16>
__global__ __launch_bounds__(256) void gemm_pipe_kernel(const __hip_bfloat16* __restrict__ A,
                                                        const __hip_bfloat16* __restrict__ Bt,
                                                        void* __restrict__ Cp,
                                                        int M, int N, int K, int nbx) {
    __shared__ __hip_bfloat16 As[3][2048];   // 3 x [64 rows][32 k]
    __shared__ __hip_bfloat16 Bs[3][4096];   // 3 x [128 rows][32 k]

    const int nwg = gridDim.x, cpx = nwg >> 3, bid = blockIdx.x;
    const int swz = (bid & 7) * cpx + (bid >> 3);
    const int bm = (swz / nbx) * 64, bn = (swz % nbx) * 128;

    const int t = threadIdx.x, w = t >> 6, l = t & 63;
    const int wr = (w >> 1) * 32, wc = (w & 1) * 64;
    const int lr = l & 15;
    const int rdslot = (((l >> 4) ^ ((lr >> 1) & 3))) * 8;
    const int srow = w * 16 + (l >> 2);                 // staging row (16-row wave stripe)
    const int scol = (((l & 3) ^ ((l >> 3) & 3))) * 8;  // pre-swizzled source slot
    const int ldsoff = w * 512;                         // w*16 rows * 32 elems

    const __hip_bfloat16* ga0 = A + (size_t)(bm + srow) * K + scol;
    const __hip_bfloat16* gb0 = Bt + (size_t)(bn + srow) * K + scol;
    const size_t half = (size_t)64 * K;

    fx4 acc[2][4];
#pragma unroll
    for (int m = 0; m < 2; m++)
#pragma unroll
        for (int n = 0; n < 4; n++) acc[m][n] = (fx4){0.f, 0.f, 0.f, 0.f};

    const int T = K >> 5;

#define STAGE(kt, b)                                              \
    do {                                                          \
        const __hip_bfloat16* ga = ga0 + (kt) * 32;               \
        const __hip_bfloat16* gb = gb0 + (kt) * 32;               \
        GL_LDS16(ga,        &As[(b)][ldsoff]);                    \
        GL_LDS16(gb,        &Bs[(b)][ldsoff]);                    \
        GL_LDS16(gb + half, &Bs[(b)][2048 + ldsoff]);             \
    } while (0)

    STAGE(0, 0);
    STAGE(1, 1);

    for (int i = 0; i < T; i++) {
        const int r = i % 3;
        if (i + 1 < T) asm volatile("s_waitcnt vmcnt(3)" ::: "memory");
        else           asm volatile("s_waitcnt vmcnt(0)" ::: "memory");
        __builtin_amdgcn_s_barrier();
        asm volatile("" ::: "memory");
        if (i + 2 < T) STAGE(i + 2, (i + 2) % 3);

        bx8 af[2], bf[4];
#pragma unroll
        for (int m = 0; m < 2; m++)
            af[m] = *reinterpret_cast<const bx8*>(&As[r][(wr + m * 16 + lr) * 32 + rdslot]);
#pragma unroll
        for (int n = 0; n < 4; n++)
            bf[n] = *reinterpret_cast<const bx8*>(&Bs[r][(wc + n * 16 + lr) * 32 + rdslot]);
#pragma unroll
        for (int m = 0; m < 2; m++)
#pragma unroll
            for (int n = 0; n < 4; n++)
                acc[m][n] = __builtin_amdgcn_mfma_f32_16x16x32_bf16(af[m], bf[n], acc[m][n], 0, 0, 0);
    }
#undef STAGE

    const int lq = (l >> 4) * 4;
#pragma unroll
    for (int m = 0; m < 2; m++)
#pragma unroll
        for (int n = 0; n < 4; n++)
#pragma unroll
            for (int r2 = 0; r2 < 4; r2++) {
                int row = bm + wr + m * 16 + lq + r2;
                int col = bn + wc + n * 16 + lr;
                float v = acc[m][n][r2];
                if (OUTBF16)
                    ((__hip_bfloat16*)Cp)[(size_t)row * N + col] = __float2bfloat16(v);
                else
                    ((float*)Cp)[(size_t)row * N + col] = v;
            }
}

// ---------------- MFMA sliding-window flash attention, swapped-operand softmax (frozen R12) ----------------
__global__ __launch_bounds__(512, 4) void attn_kernel(const __hip_bfloat16* __restrict__ Q,
                                                      const __hip_bfloat16* __restrict__ Kg,
                                                      const __hip_bfloat16* __restrict__ Vtg,
                                                      __hip_bfloat16* __restrict__ Ab) {
    __shared__ __hip_bfloat16 Ks[64 * 64];
    __shared__ __hip_bfloat16 Vs[64 * 64];
    __shared__ __hip_bfloat16 Ps[QBLK * 64];

    const int bid = blockIdx.x;
    const int swz = (bid & 7) * 64 + (bid >> 3);
    const int h = swz >> 4, qi = swz & 15;
    const int qb = qi * QBLK;
    const int kvh = h >> 2;

    const int t = threadIdx.x, w = t >> 6, l = t & 63;
    const int lr = l & 15, g = l >> 4, lk = g * 8;
    const int qbw = qb + 16 * w;      // this wave's 16 q-rows
    const int prow = 16 * w + lr;     // this lane's q-row in Ps
    const int psz = (prow & 7) << 4;

    char* KsB = (char*)Ks;
    char* VsB = (char*)Vs;
    char* PsB = (char*)Ps;

    // hoisted Q fragments (B-operand; lane holds q-row lr)
    bx8 qa[2];
#pragma unroll
    for (int ks = 0; ks < 2; ks++)
        qa[ks] = *reinterpret_cast<const bx8*>(
            &Q[(size_t)(qbw + lr) * QKVN + h * HD + ks * 32 + lk]);

    fx4 ot[4];
#pragma unroll
    for (int n = 0; n < 4; n++) ot[n] = (fx4){0.f, 0.f, 0.f, 0.f};
    float mrow = -1e30f, srow = 0.f;

    const int k0_first = (qb >= 1024) ? (qb - 1024) : 0;
    const int k0_last  = qb + 64;
    const int wmax = qbw + 15;
    const int rowq = qbw + lr;        // this lane's q-row (global)

    // staging: 512 threads cover 64 rows x 8 us8-cols, one K + one V load each
    const int sr = t >> 3, sc8 = (t & 7) * 8;
    const int dst = sr * 128 + ((sc8 * 2) ^ ((sr & 7) << 4));

    for (int k0 = k0_first; k0 <= k0_last; k0 += 64) {
        us8 kv = *reinterpret_cast<const us8*>(&Kg[(size_t)(k0 + sr) * QKVN + kvh * HD + sc8]);
        us8 vv = *reinterpret_cast<const us8*>(&Vtg[(size_t)(kvh * HD + sr) * S_LEN + k0 + sc8]);
        *reinterpret_cast<us8*>(KsB + dst) = kv;
        *reinterpret_cast<us8*>(VsB + dst) = vv;
        __syncthreads();

        if (k0 <= wmax) {
            // K fragments (A-operand: rows = keys)
            bx8 kb[4][2];
#pragma unroll
            for (int n = 0; n < 4; n++)
#pragma unroll
                for (int ks = 0; ks < 2; ks++) {
                    int row = 16 * n + lr;
                    kb[n][ks] = *reinterpret_cast<const bx8*>(
                        KsB + row * 128 + (((ks * 64) + 16 * g) ^ ((row & 7) << 4)));
                }
            // S^T = K · Q^T : rows=keys (16n+4g+r), cols=q (lr)
            fx4 sc[4];
#pragma unroll
            for (int n = 0; n < 4; n++) {
                sc[n] = __builtin_amdgcn_mfma_f32_16x16x32_bf16(kb[n][0], qa[0],
                                                                (fx4){0.f, 0.f, 0.f, 0.f}, 0, 0, 0);
                sc[n] = __builtin_amdgcn_mfma_f32_16x16x32_bf16(kb[n][1], qa[1], sc[n], 0, 0, 0);
            }
            // scale + sliding-window mask (interior tiles skip the mask)
            const bool interior = (k0 + 63 <= qbw) && (k0 >= qbw - 1008);
            if (interior) {
#pragma unroll
                for (int n = 0; n < 4; n++)
#pragma unroll
                    for (int r = 0; r < 4; r++) sc[n][r] *= 0.125f;
            } else {
#pragma unroll
                for (int n = 0; n < 4; n++)
#pragma unroll
                    for (int r = 0; r < 4; r++) {
                        int key = k0 + 16 * n + 4 * g + r;
                        bool valid = (key <= rowq) && (key >= rowq - (WINDOW - 1));
                        sc[n][r] = valid ? sc[n][r] * 0.125f : -1e30f;
                    }
            }
            // in-register row max
            float tmax = fmaxf(fmaxf(sc[0][0], sc[0][1]), fmaxf(sc[0][2], sc[0][3]));
#pragma unroll
            for (int n = 1; n < 4; n++)
                tmax = fmaxf(tmax, fmaxf(fmaxf(sc[n][0], sc[n][1]), fmaxf(sc[n][2], sc[n][3])));
            tmax = fmaxf(tmax, __shfl_xor(tmax, 16));
            tmax = fmaxf(tmax, __shfl_xor(tmax, 32));
            float mn = fmaxf(mrow, tmax);
            float fs = __expf(mrow - mn);
            mrow = mn;
            // exp + P^T write (packed b64, lane's own row) + sum
            float ps = 0.f;
#pragma unroll
            for (int n = 0; n < 4; n++) {
#pragma unroll
                for (int r = 0; r < 4; r++) {
                    float p = __expf(sc[n][r] - mn);
                    sc[n][r] = p;
                    ps += p;
                }
                __hip_bfloat16 pk[4] __attribute__((aligned(8)));
                pk[0] = __float2bfloat16(sc[n][0]); pk[1] = __float2bfloat16(sc[n][1]);
                pk[2] = __float2bfloat16(sc[n][2]); pk[3] = __float2bfloat16(sc[n][3]);
                *reinterpret_cast<unsigned long long*>(PsB + prow * 128 + ((32 * n + 8 * g) ^ psz)) =
                    *reinterpret_cast<unsigned long long*>(pk);
            }
            ps += __shfl_xor(ps, 16);
            ps += __shfl_xor(ps, 32);
            srow = srow * fs + ps;
#pragma unroll
            for (int n = 0; n < 4; n++)
#pragma unroll
                for (int r = 0; r < 4; r++) ot[n][r] *= fs;
            // V fragments (A-operand: rows = d) + P fragments (B-operand: rows = q)
            bx8 vb[4][2];
#pragma unroll
            for (int n = 0; n < 4; n++)
#pragma unroll
                for (int ks = 0; ks < 2; ks++) {
                    int row = 16 * n + lr;
                    vb[n][ks] = *reinterpret_cast<const bx8*>(
                        VsB + row * 128 + (((ks * 64) + 16 * g) ^ ((row & 7) << 4)));
                }
            bx8 pb[2];
#pragma unroll
            for (int ks = 0; ks < 2; ks++)
                pb[ks] = *reinterpret_cast<const bx8*>(
                    PsB + prow * 128 + (((ks * 64) + 16 * g) ^ psz));
            // O^T += V^T · P : rows=d (16n+4g+r), cols=q (lr)
#pragma unroll
            for (int n = 0; n < 4; n++) {
                ot[n] = __builtin_amdgcn_mfma_f32_16x16x32_bf16(vb[n][0], pb[0], ot[n], 0, 0, 0);
                ot[n] = __builtin_amdgcn_mfma_f32_16x16x32_bf16(vb[n][1], pb[1], ot[n], 0, 0, 0);
            }
        }
        __syncthreads();
    }

    // ---- epilogue: normalize, O^T frags -> Ps as [q][d] (b64+XOR), then
    // cooperative coalesced row-major store to Ab (128 rows x 8 chunks) ----
    const float inv = 1.f / srow;
#pragma unroll
    for (int n = 0; n < 4; n++) {
        __hip_bfloat16 pk[4] __attribute__((aligned(8)));
#pragma unroll
        for (int r = 0; r < 4; r++) pk[r] = __float2bfloat16(ot[n][r] * inv);
        *reinterpret_cast<unsigned long long*>(PsB + prow * 128 + ((32 * n + 8 * g) ^ psz)) =
            *reinterpret_cast<unsigned long long*>(pk);
    }
    __syncthreads();
#pragma unroll
    for (int j = 0; j < 2; j++) {
        const int row = (t >> 3) + 64 * j, c = t & 7;   // 128 rows x 8 us8-chunks
        us8 v = *reinterpret_cast<const us8*>(PsB + row * 128 + ((c * 16) ^ ((row & 7) << 4)));
        *reinterpret_cast<us8*>(&Ab[(size_t)(qb + row) * HID + h * HD + c * 8]) = v;
    }
}

extern "C" void kernel_launch(void* const* d_in, const int* in_sizes, int n_in,
                              void* d_out, int out_size, void* d_ws, size_t ws_size,
                              hipStream_t stream) {
    const float* hs = (const float*)d_in[0];
    const float* Wq = (const float*)d_in[1];
    const float* Wk = (const float*)d_in[2];
    const float* Wv = (const float*)d_in[3];
    const float* Wo = (const float*)d_in[4];

    float* ws   = (float*)d_ws;
    float* cosT = ws;                  // 65536 f32
    float* sinT = cosT + 65536;        // 65536 f32
    __hip_bfloat16* hsb    = (__hip_bfloat16*)(sinT + 65536);   // [2048][2048]
    __hip_bfloat16* WqkvT  = hsb + 4194304;                     // [3072][2048]: Wq|Wk|Wv rows
    __hip_bfloat16* WoT    = WqkvT + 6291456;                   // [2048][2048]
    __hip_bfloat16* QKVb   = WoT + 4194304;                     // [2048][3072]
    __hip_bfloat16* Vt     = QKVb + 6291456;                    // [512][2048]
    __hip_bfloat16* Ab     = hsb;                               // alias: hsb dead after QKV gemm

    // prep: tables + hs->bf16 + weight transposes (one dispatch)
    prep_kernel<<<12544, 256, 0, stream>>>(hs, Wq, Wk, Wv, Wo, cosT, sinT, hsb, WqkvT, WoT);

    // fused QKV projection: [2048][3072] = hsb @ WqkvT^T  (64x128 tiles, 768 blocks)
    gemm_pipe_kernel<1><<<768, 256, 0, stream>>>(hsb, WqkvT, QKVb, 2048, QKVN, 2048, 24);

    // RoPE (Q+K) + V transpose (one dispatch)
    ropev_kernel<<<11264, 256, 0, stream>>>(QKVb, Vt, cosT, sinT);

    // attention writes row-major Ab directly
    attn_kernel<<<512, 512, 0, stream>>>(QKVb, QKVb + 2048, Vt, Ab);

    // output projection: d_out = Ab @ WoT^T  (64x128 tiles, 512 blocks)
    gemm_pipe_kernel<0><<<512, 256, 0, stream>>>(Ab, WoT, d_out, 2048, 2048, 2048, 16);
}

// Round 14
// 144.670 us; speedup vs baseline: 1.3657x; 1.0047x over previous
//
#include <hip/hip_runtime.h>
#include <hip/hip_bf16.h>
#include <math.h>

#define S_LEN 2048
#define HID 2048
#define NH 32
#define NKV 8
#define HD 64
#define WINDOW 1024
#define QBLK 128
#define QKVN 3072   // fused Q(2048) | K(512) | V(512) columns

typedef __attribute__((ext_vector_type(8))) short bx8;          // 8 bf16 (4 VGPRs) — MFMA A/B frag
typedef __attribute__((ext_vector_type(4))) float fx4;          // MFMA C/D frag
typedef __attribute__((ext_vector_type(8))) unsigned short us8; // 8 bf16 raw

#define GL_LDS16(gp, lp) \
    __builtin_amdgcn_global_load_lds((__attribute__((address_space(1))) const void*)(gp), \
                                     (__attribute__((address_space(3))) void*)(lp), 16, 0, 0)

// ---------------- prep: rope tables + hs conv + 4 weight transposes, ONE dispatch ----------------
__global__ __launch_bounds__(256) void prep_kernel(const float* __restrict__ hs,
                                                   const float* __restrict__ Wq,
                                                   const float* __restrict__ Wk,
                                                   const float* __restrict__ Wv,
                                                   const float* __restrict__ Wo,
                                                   float* __restrict__ cosT, float* __restrict__ sinT,
                                                   __hip_bfloat16* __restrict__ hsb,
                                                   __hip_bfloat16* __restrict__ WqkvT,
                                                   __hip_bfloat16* __restrict__ WoT) {
    __shared__ float tile[32][33];
    int b = blockIdx.x, t = threadIdx.x;
    if (b < 256) {
        int idx = b * 256 + t;           // s*32 + f
        int s = idx >> 5, f = idx & 31;
        double inv = exp(-2.0 * (double)f / 64.0 * log(500000.0));
        double ang = (double)s * inv;
        cosT[idx] = (float)cos(ang);
        sinT[idx] = (float)sin(ang);
        return;
    }
    b -= 256;
    if (b < 2048) {
        int i = (b * 256 + t) * 8;
        float4 a = *reinterpret_cast<const float4*>(&hs[i]);
        float4 c = *reinterpret_cast<const float4*>(&hs[i + 4]);
        __hip_bfloat16 o[8] __attribute__((aligned(16)));
        o[0] = __float2bfloat16(a.x); o[1] = __float2bfloat16(a.y);
        o[2] = __float2bfloat16(a.z); o[3] = __float2bfloat16(a.w);
        o[4] = __float2bfloat16(c.x); o[5] = __float2bfloat16(c.y);
        o[6] = __float2bfloat16(c.z); o[7] = __float2bfloat16(c.w);
        *reinterpret_cast<bx8*>(&hsb[i]) = *reinterpret_cast<bx8*>(o);
        return;
    }
    b -= 2048;
    const float* src; __hip_bfloat16* dst; int Nd, bx, by;
    if (b < 4096)      { src = Wq; dst = WqkvT;                        Nd = 2048; bx = b & 63; by = b >> 6; }
    else if (b < 5120) { b -= 4096; src = Wk; dst = WqkvT + (size_t)2048 * 2048; Nd = 512; bx = b & 15; by = b >> 4; }
    else if (b < 6144) { b -= 5120; src = Wv; dst = WqkvT + (size_t)2560 * 2048; Nd = 512; bx = b & 15; by = b >> 4; }
    else               { b -= 6144; src = Wo; dst = WoT;               Nd = 2048; bx = b & 63; by = b >> 6; }
    int n0 = bx * 32, k0 = by * 32, tx = t & 31, ty = t >> 5;  // 32 x 8
#pragma unroll
    for (int i = 0; i < 4; i++)
        tile[ty + 8 * i][tx] = src[(size_t)(k0 + ty + 8 * i) * Nd + n0 + tx];
    __syncthreads();
#pragma unroll
    for (int i = 0; i < 4; i++)
        dst[(size_t)(n0 + ty + 8 * i) * 2048 + k0 + tx] = __float2bfloat16(tile[tx][ty + 8 * i]);
}

// ---------------- rope (Q+K) + vtrans, ONE dispatch ----------------
__global__ __launch_bounds__(256) void ropev_kernel(__hip_bfloat16* __restrict__ QKV,
                                                    __hip_bfloat16* __restrict__ Vt,
                                                    const float* __restrict__ cosT,
                                                    const float* __restrict__ sinT) {
    __shared__ __hip_bfloat16 tile[32][33];
    int b = blockIdx.x, t = threadIdx.x;
    if (b < 10240) {
        int idx = b * 256 + t;           // s*(40*32) + head*32 + f
        int f = idx & 31;
        int head = (idx >> 5) % (NH + NKV);
        int s = idx / ((NH + NKV) * 32);
        float c  = cosT[(s << 5) + f];
        float sn = sinT[(s << 5) + f];
        __hip_bfloat16* p = (head < NH) ? (QKV + (size_t)s * QKVN + head * HD)
                                        : (QKV + (size_t)s * QKVN + 2048 + (head - NH) * HD);
        float x1 = __bfloat162float(p[f]), x2 = __bfloat162float(p[f + 32]);
        p[f]      = __float2bfloat16(x1 * c - x2 * sn);
        p[f + 32] = __float2bfloat16(x2 * c + x1 * sn);
        return;
    }
    b -= 10240;
    int s0 = (b & 63) * 32, d0 = (b >> 6) * 32;
    int tx = t & 31, ty = t >> 5;  // 32 x 8
#pragma unroll
    for (int i = 0; i < 4; i++)
        tile[ty + 8 * i][tx] = QKV[(size_t)(s0 + ty + 8 * i) * QKVN + 2560 + d0 + tx];
    __syncthreads();
#pragma unroll
    for (int i = 0; i < 4; i++)
        Vt[(size_t)(d0 + ty + 8 * i) * S_LEN + s0 + tx] = tile[tx][ty + 8 * i];
}

// ---------------- pipelined bf16 MFMA GEMM, 64x128 tile, XCD N-striped (R14) ----------------
// Each XCD owns an N-column stripe (stripe n-tiles): its B panel (stripe*128
// cols x K) is ~1.5MB -> L2-resident across all m-tiles; same-m blocks adjacent.
template <int OUTBF16>
__global__ __launch_bounds__(256) void gemm_pipe_kernel(const __hip_bfloat16* __restrict__ A,
                                                        const __hip_bfloat16* __restrict__ Bt,
                                                        void* __restrict__ Cp,
                                                        int M, int N, int K, int stripe) {
    __shared__ __hip_bfloat16 As[3][2048];   // 3 x [64 rows][32 k]
    __shared__ __hip_bfloat16 Bs[3][4096];   // 3 x [128 rows][32 k]

    // XCD N-stripe mapping: bid&7 = XCD (dispatch round-robin), j walks
    // (m, n-within-stripe) with n fastest so same-m blocks are adjacent.
    const int bid = blockIdx.x;
    const int x = bid & 7, j = bid >> 3;
    const int bn = (x * stripe + j % stripe) * 128;
    const int bm = (j / stripe) * 64;

    const int t = threadIdx.x, w = t >> 6, l = t & 63;
    const int wr = (w >> 1) * 32, wc = (w & 1) * 64;
    const int lr = l & 15;
    const int rdslot = (((l >> 4) ^ ((lr >> 1) & 3))) * 8;
    const int srow = w * 16 + (l >> 2);                 // staging row (16-row wave stripe)
    const int scol = (((l & 3) ^ ((l >> 3) & 3))) * 8;  // pre-swizzled source slot
    const int ldsoff = w * 512;                         // w*16 rows * 32 elems

    const __hip_bfloat16* ga0 = A + (size_t)(bm + srow) * K + scol;
    const __hip_bfloat16* gb0 = Bt + (size_t)(bn + srow) * K + scol;
    const size_t half = (size_t)64 * K;

    fx4 acc[2][4];
#pragma unroll
    for (int m = 0; m < 2; m++)
#pragma unroll
        for (int n = 0; n < 4; n++) acc[m][n] = (fx4){0.f, 0.f, 0.f, 0.f};

    const int T = K >> 5;

#define STAGE(kt, b)                                              \
    do {                                                          \
        const __hip_bfloat16* ga = ga0 + (kt) * 32;               \
        const __hip_bfloat16* gb = gb0 + (kt) * 32;               \
        GL_LDS16(ga,        &As[(b)][ldsoff]);                    \
        GL_LDS16(gb,        &Bs[(b)][ldsoff]);                    \
        GL_LDS16(gb + half, &Bs[(b)][2048 + ldsoff]);             \
    } while (0)

    STAGE(0, 0);
    STAGE(1, 1);

    for (int i = 0; i < T; i++) {
        const int r = i % 3;
        if (i + 1 < T) asm volatile("s_waitcnt vmcnt(3)" ::: "memory");
        else           asm volatile("s_waitcnt vmcnt(0)" ::: "memory");
        __builtin_amdgcn_s_barrier();
        asm volatile("" ::: "memory");
        if (i + 2 < T) STAGE(i + 2, (i + 2) % 3);

        bx8 af[2], bf[4];
#pragma unroll
        for (int m = 0; m < 2; m++)
            af[m] = *reinterpret_cast<const bx8*>(&As[r][(wr + m * 16 + lr) * 32 + rdslot]);
#pragma unroll
        for (int n = 0; n < 4; n++)
            bf[n] = *reinterpret_cast<const bx8*>(&Bs[r][(wc + n * 16 + lr) * 32 + rdslot]);
#pragma unroll
        for (int m = 0; m < 2; m++)
#pragma unroll
            for (int n = 0; n < 4; n++)
                acc[m][n] = __builtin_amdgcn_mfma_f32_16x16x32_bf16(af[m], bf[n], acc[m][n], 0, 0, 0);
    }
#undef STAGE

    const int lq = (l >> 4) * 4;
#pragma unroll
    for (int m = 0; m < 2; m++)
#pragma unroll
        for (int n = 0; n < 4; n++)
#pragma unroll
            for (int r2 = 0; r2 < 4; r2++) {
                int row = bm + wr + m * 16 + lq + r2;
                int col = bn + wc + n * 16 + lr;
                float v = acc[m][n][r2];
                if (OUTBF16)
                    ((__hip_bfloat16*)Cp)[(size_t)row * N + col] = __float2bfloat16(v);
                else
                    ((float*)Cp)[(size_t)row * N + col] = v;
            }
}

// ---------------- MFMA sliding-window flash attention, swapped-operand softmax (frozen R12) ----------------
__global__ __launch_bounds__(512, 4) void attn_kernel(const __hip_bfloat16* __restrict__ Q,
                                                      const __hip_bfloat16* __restrict__ Kg,
                                                      const __hip_bfloat16* __restrict__ Vtg,
                                                      __hip_bfloat16* __restrict__ Ab) {
    __shared__ __hip_bfloat16 Ks[64 * 64];
    __shared__ __hip_bfloat16 Vs[64 * 64];
    __shared__ __hip_bfloat16 Ps[QBLK * 64];

    const int bid = blockIdx.x;
    const int swz = (bid & 7) * 64 + (bid >> 3);
    const int h = swz >> 4, qi = swz & 15;
    const int qb = qi * QBLK;
    const int kvh = h >> 2;

    const int t = threadIdx.x, w = t >> 6, l = t & 63;
    const int lr = l & 15, g = l >> 4, lk = g * 8;
    const int qbw = qb + 16 * w;      // this wave's 16 q-rows
    const int prow = 16 * w + lr;     // this lane's q-row in Ps
    const int psz = (prow & 7) << 4;

    char* KsB = (char*)Ks;
    char* VsB = (char*)Vs;
    char* PsB = (char*)Ps;

    // hoisted Q fragments (B-operand; lane holds q-row lr)
    bx8 qa[2];
#pragma unroll
    for (int ks = 0; ks < 2; ks++)
        qa[ks] = *reinterpret_cast<const bx8*>(
            &Q[(size_t)(qbw + lr) * QKVN + h * HD + ks * 32 + lk]);

    fx4 ot[4];
#pragma unroll
    for (int n = 0; n < 4; n++) ot[n] = (fx4){0.f, 0.f, 0.f, 0.f};
    float mrow = -1e30f, srow = 0.f;

    const int k0_first = (qb >= 1024) ? (qb - 1024) : 0;
    const int k0_last  = qb + 64;
    const int wmax = qbw + 15;
    const int rowq = qbw + lr;        // this lane's q-row (global)

    // staging: 512 threads cover 64 rows x 8 us8-cols, one K + one V load each
    const int sr = t >> 3, sc8 = (t & 7) * 8;
    const int dst = sr * 128 + ((sc8 * 2) ^ ((sr & 7) << 4));

    for (int k0 = k0_first; k0 <= k0_last; k0 += 64) {
        us8 kv = *reinterpret_cast<const us8*>(&Kg[(size_t)(k0 + sr) * QKVN + kvh * HD + sc8]);
        us8 vv = *reinterpret_cast<const us8*>(&Vtg[(size_t)(kvh * HD + sr) * S_LEN + k0 + sc8]);
        *reinterpret_cast<us8*>(KsB + dst) = kv;
        *reinterpret_cast<us8*>(VsB + dst) = vv;
        __syncthreads();

        if (k0 <= wmax) {
            // K fragments (A-operand: rows = keys)
            bx8 kb[4][2];
#pragma unroll
            for (int n = 0; n < 4; n++)
#pragma unroll
                for (int ks = 0; ks < 2; ks++) {
                    int row = 16 * n + lr;
                    kb[n][ks] = *reinterpret_cast<const bx8*>(
                        KsB + row * 128 + (((ks * 64) + 16 * g) ^ ((row & 7) << 4)));
                }
            // S^T = K · Q^T : rows=keys (16n+4g+r), cols=q (lr)
            fx4 sc[4];
#pragma unroll
            for (int n = 0; n < 4; n++) {
                sc[n] = __builtin_amdgcn_mfma_f32_16x16x32_bf16(kb[n][0], qa[0],
                                                                (fx4){0.f, 0.f, 0.f, 0.f}, 0, 0, 0);
                sc[n] = __builtin_amdgcn_mfma_f32_16x16x32_bf16(kb[n][1], qa[1], sc[n], 0, 0, 0);
            }
            // scale + sliding-window mask (interior tiles skip the mask)
            const bool interior = (k0 + 63 <= qbw) && (k0 >= qbw - 1008);
            if (interior) {
#pragma unroll
                for (int n = 0; n < 4; n++)
#pragma unroll
                    for (int r = 0; r < 4; r++) sc[n][r] *= 0.125f;
            } else {
#pragma unroll
                for (int n = 0; n < 4; n++)
#pragma unroll
                    for (int r = 0; r < 4; r++) {
                        int key = k0 + 16 * n + 4 * g + r;
                        bool valid = (key <= rowq) && (key >= rowq - (WINDOW - 1));
                        sc[n][r] = valid ? sc[n][r] * 0.125f : -1e30f;
                    }
            }
            // in-register row max
            float tmax = fmaxf(fmaxf(sc[0][0], sc[0][1]), fmaxf(sc[0][2], sc[0][3]));
#pragma unroll
            for (int n = 1; n < 4; n++)
                tmax = fmaxf(tmax, fmaxf(fmaxf(sc[n][0], sc[n][1]), fmaxf(sc[n][2], sc[n][3])));
            tmax = fmaxf(tmax, __shfl_xor(tmax, 16));
            tmax = fmaxf(tmax, __shfl_xor(tmax, 32));
            float mn = fmaxf(mrow, tmax);
            float fs = __expf(mrow - mn);
            mrow = mn;
            // exp + P^T write (packed b64, lane's own row) + sum
            float ps = 0.f;
#pragma unroll
            for (int n = 0; n < 4; n++) {
#pragma unroll
                for (int r = 0; r < 4; r++) {
                    float p = __expf(sc[n][r] - mn);
                    sc[n][r] = p;
                    ps += p;
                }
                __hip_bfloat16 pk[4] __attribute__((aligned(8)));
                pk[0] = __float2bfloat16(sc[n][0]); pk[1] = __float2bfloat16(sc[n][1]);
                pk[2] = __float2bfloat16(sc[n][2]); pk[3] = __float2bfloat16(sc[n][3]);
                *reinterpret_cast<unsigned long long*>(PsB + prow * 128 + ((32 * n + 8 * g) ^ psz)) =
                    *reinterpret_cast<unsigned long long*>(pk);
            }
            ps += __shfl_xor(ps, 16);
            ps += __shfl_xor(ps, 32);
            srow = srow * fs + ps;
#pragma unroll
            for (int n = 0; n < 4; n++)
#pragma unroll
                for (int r = 0; r < 4; r++) ot[n][r] *= fs;
            // V fragments (A-operand: rows = d) + P fragments (B-operand: rows = q)
            bx8 vb[4][2];
#pragma unroll
            for (int n = 0; n < 4; n++)
#pragma unroll
                for (int ks = 0; ks < 2; ks++) {
                    int row = 16 * n + lr;
                    vb[n][ks] = *reinterpret_cast<const bx8*>(
                        VsB + row * 128 + (((ks * 64) + 16 * g) ^ ((row & 7) << 4)));
                }
            bx8 pb[2];
#pragma unroll
            for (int ks = 0; ks < 2; ks++)
                pb[ks] = *reinterpret_cast<const bx8*>(
                    PsB + prow * 128 + (((ks * 64) + 16 * g) ^ psz));
            // O^T += V^T · P : rows=d (16n+4g+r), cols=q (lr)
#pragma unroll
            for (int n = 0; n < 4; n++) {
                ot[n] = __builtin_amdgcn_mfma_f32_16x16x32_bf16(vb[n][0], pb[0], ot[n], 0, 0, 0);
                ot[n] = __builtin_amdgcn_mfma_f32_16x16x32_bf16(vb[n][1], pb[1], ot[n], 0, 0, 0);
            }
        }
        __syncthreads();
    }

    // ---- epilogue: normalize, O^T frags -> Ps as [q][d] (b64+XOR), then
    // cooperative coalesced row-major store to Ab (128 rows x 8 chunks) ----
    const float inv = 1.f / srow;
#pragma unroll
    for (int n = 0; n < 4; n++) {
        __hip_bfloat16 pk[4] __attribute__((aligned(8)));
#pragma unroll
        for (int r = 0; r < 4; r++) pk[r] = __float2bfloat16(ot[n][r] * inv);
        *reinterpret_cast<unsigned long long*>(PsB + prow * 128 + ((32 * n + 8 * g) ^ psz)) =
            *reinterpret_cast<unsigned long long*>(pk);
    }
    __syncthreads();
#pragma unroll
    for (int j = 0; j < 2; j++) {
        const int row = (t >> 3) + 64 * j, c = t & 7;   // 128 rows x 8 us8-chunks
        us8 v = *reinterpret_cast<const us8*>(PsB + row * 128 + ((c * 16) ^ ((row & 7) << 4)));
        *reinterpret_cast<us8*>(&Ab[(size_t)(qb + row) * HID + h * HD + c * 8]) = v;
    }
}

extern "C" void kernel_launch(void* const* d_in, const int* in_sizes, int n_in,
                              void* d_out, int out_size, void* d_ws, size_t ws_size,
                              hipStream_t stream) {
    const float* hs = (const float*)d_in[0];
    const float* Wq = (const float*)d_in[1];
    const float* Wk = (const float*)d_in[2];
    const float* Wv = (const float*)d_in[3];
    const float* Wo = (const float*)d_in[4];

    float* ws   = (float*)d_ws;
    float* cosT = ws;                  // 65536 f32
    float* sinT = cosT + 65536;        // 65536 f32
    __hip_bfloat16* hsb    = (__hip_bfloat16*)(sinT + 65536);   // [2048][2048]
    __hip_bfloat16* WqkvT  = hsb + 4194304;                     // [3072][2048]: Wq|Wk|Wv rows
    __hip_bfloat16* WoT    = WqkvT + 6291456;                   // [2048][2048]
    __hip_bfloat16* QKVb   = WoT + 4194304;                     // [2048][3072]
    __hip_bfloat16* Vt     = QKVb + 6291456;                    // [512][2048]
    __hip_bfloat16* Ab     = hsb;                               // alias: hsb dead after QKV gemm

    // prep: tables + hs->bf16 + weight transposes (one dispatch)
    prep_kernel<<<12544, 256, 0, stream>>>(hs, Wq, Wk, Wv, Wo, cosT, sinT, hsb, WqkvT, WoT);

    // fused QKV projection (64x128 tiles, 768 blocks, XCD stripe=3)
    gemm_pipe_kernel<1><<<768, 256, 0, stream>>>(hsb, WqkvT, QKVb, 2048, QKVN, 2048, 3);

    // RoPE (Q+K) + V transpose (one dispatch)
    ropev_kernel<<<11264, 256, 0, stream>>>(QKVb, Vt, cosT, sinT);

    // attention writes row-major Ab directly
    attn_kernel<<<512, 512, 0, stream>>>(QKVb, QKVb + 2048, Vt, Ab);

    // output projection (64x128 tiles, 512 blocks, XCD stripe=2)
    gemm_pipe_kernel<0><<<512, 256, 0, stream>>>(Ab, WoT, d_out, 2048, 2048, 2048, 2);
}